// Round 3
// baseline (292.249 us; speedup 1.0000x reference)
//
#include <hip/hip_runtime.h>
#include <hip/hip_bf16.h>
#include <cstdint>
#include <cstddef>

namespace {

constexpr int BATCH = 16;
constexpr int LEN   = 8192;
constexpr int CIN   = 257;
constexpr int CS    = 256;   // space channels
constexpr int NF    = 4096;  // output frames
constexpr int LPAD  = LEN + 4;   // 8196 padded rows per batch (2 each side)
constexpr int NKS   = 40;        // K-steps of 32 (K = 1280)
constexpr int MT    = 64;        // frames per block

// workspace layout
constexpr int    XS_ROWS   = BATCH * LPAD;                 // 131136
constexpr size_t XS_BYTES  = (size_t)(XS_ROWS + 16) * 512; // +16 rows staging slack
constexpr size_t RSQ_OFF   = XS_BYTES;
constexpr size_t RSQ_BYTES = (size_t)XS_ROWS * 4;
constexpr size_t WPK_OFF   = RSQ_OFF + RSQ_BYTES;
constexpr size_t WPK_BYTES = (size_t)16 * NKS * 64 * 8 * 2; // 655360 packed B
constexpr size_t W0_OFF    = WPK_OFF + WPK_BYTES + 4096;    // 4K pad (prefetch slack)
constexpr size_t WS_NEED   = W0_OFF + 1024;

typedef __attribute__((ext_vector_type(8))) short short8;
typedef __attribute__((ext_vector_type(8))) unsigned short ushort8v;
typedef __attribute__((ext_vector_type(4))) float f32x4;

__device__ __forceinline__ unsigned short f2bf_bits(float f) {
  union { __hip_bfloat16 h; unsigned short u; } cv;
  cv.h = __float2bfloat16(f);
  return cv.u;
}

__device__ __forceinline__ void async_cp16(const void* g, void* l) {
  __builtin_amdgcn_global_load_lds(
      (const __attribute__((address_space(1))) void*)g,
      (__attribute__((address_space(3))) void*)l,
      16, 0, 0);
}

} // namespace

// ---------------- prep 1: W (257x1281 f32) -> packed B fragments + w0[256] f32
// wpk[((nf*40 + ks)*64 + lane)*8 + j] = bf16(W[nf*16+(lane&15)+1][1 + ks*32 + (lane>>4)*8 + j])
__global__ void prep_w_kernel(const float* __restrict__ W,
                              __hip_bfloat16* __restrict__ wpk,
                              float* __restrict__ w0) {
  int t = blockIdx.x * 256 + threadIdx.x;   // 0..40959
  int lane = t & 63;
  int ks   = (t >> 6) % NKS;
  int nf   = t / (NKS * 64);
  int n    = nf * 16 + (lane & 15);
  int kh   = lane >> 4;
  const float* src = W + (size_t)(n + 1) * 1281 + 1 + ks * 32 + kh * 8;
  ushort8v pk;
#pragma unroll
  for (int j = 0; j < 8; ++j) pk[j] = f2bf_bits(src[j]);
  *(ushort8v*)(wpk + (size_t)t * 8) = pk;
  if (t < 256) w0[t] = W[(size_t)(t + 1) * 1281];
}

// ---------------- prep 2: x f32 -> xs bf16 (padded rows) + rowsq f32
__global__ void prep_x_kernel(const float* __restrict__ x,
                              __hip_bfloat16* __restrict__ xs,
                              float* __restrict__ rowsq) {
  const int tid = threadIdx.x;
  const int bx  = blockIdx.x;
  if (bx < 8192) {
    __shared__ float4 xf4[1028];
    const float4* src = (const float4*)(x + (size_t)bx * 4112);
#pragma unroll
    for (int i = 0; i < 4; ++i) {
      int idx = i * 256 + tid;
      xf4[idx] = src[idx];
    }
    if (tid < 4) xf4[1024 + tid] = src[1024 + tid];
    __syncthreads();
    const float* xf = (const float*)xf4;
    const int row = tid >> 4, seg = tid & 15;
    const float* v = xf + row * 257 + 1 + seg * 16;
    float ss = 0.f;
    unsigned short u[16];
#pragma unroll
    for (int i = 0; i < 16; ++i) {
      float f = v[i];
      ss += f * f;
      u[i] = f2bf_bits(f);
    }
    const int b = bx >> 9;
    const int t = (bx & 511) * 16 + row;
    const size_t tpg = (size_t)b * LPAD + 2 + t;
    ushort8v* dst = (ushort8v*)((unsigned short*)xs + tpg * CS + seg * 16);
    ushort8v p0, p1;
#pragma unroll
    for (int i = 0; i < 8; ++i) { p0[i] = u[i]; p1[i] = u[8 + i]; }
    dst[0] = p0;
    dst[1] = p1;
    ss += __shfl_xor(ss, 1);
    ss += __shfl_xor(ss, 2);
    ss += __shfl_xor(ss, 4);
    ss += __shfl_xor(ss, 8);
    if (seg == 0) rowsq[tpg] = ss;
  } else {
    // zero the 64 pad rows (4 per batch) + their rowsq
    for (int i = tid; i < 64 * 128; i += 256) {
      int row = i >> 7, uo = i & 127;
      int b = row >> 2, j = row & 3;
      size_t tpg = (size_t)b * LPAD + (j < 2 ? j : 8192 + j);  // 0,1,8194,8195
      ((uint32_t*)xs)[tpg * 128 + uo] = 0;
      if (uo == 0) rowsq[tpg] = 0.0f;
    }
  }
}

// ---------------- main GEMM: barrier-free K-loop
// block: 256 thr = 4 waves; wave w computes 64 frames x 64 out-ch (n = w*64..)
// A: raw 136 rows staged ONCE in LDS (XOR-swizzled); B: direct from L2 (packed)
__global__ __launch_bounds__(256, 2) void lorentz_gemm_kernel(
    const __hip_bfloat16* __restrict__ xs,
    const __hip_bfloat16* __restrict__ wpk,
    const float* __restrict__ rowsq,
    const float* __restrict__ w0,
    const float* __restrict__ bvec,
    float* __restrict__ out) {
  __shared__ alignas(16) char A_lds[136 * 512];
  __shared__ alignas(16) float time0_s[64];
  __shared__ alignas(16) float normsq_s[64];

  const int tid   = threadIdx.x;
  const int w     = tid >> 6;        // wave id = n-slice
  const int lane  = tid & 63;
  const int row16 = lane & 15;
  const int q     = lane >> 4;

  const int bx    = blockIdx.x;
  const int b     = bx >> 6;
  const int Mblk  = (bx & 63) * MT;

  const char* xsb = (const char*)(xs + ((size_t)b * LPAD + 2 * Mblk) * CS);

  // ---- stage 136 raw rows (67 KB), swizzled: phys chunk c of row r holds
  // logical chunk c ^ ((r>>1)&15)
#pragma unroll
  for (int j = 0; j < 17; ++j) {
    int cid = (j * 4 + w) * 64 + lane;
    int r = cid >> 5, c = cid & 31;
    int sw = (r >> 1) & 15;
    async_cp16(xsb + r * 512 + ((c ^ sw) << 4), (char*)A_lds + cid * 16);
  }

  f32x4 acc[4][4];
#pragma unroll
  for (int i = 0; i < 4; ++i)
#pragma unroll
    for (int j = 0; j < 4; ++j) acc[i][j] = (f32x4){0.f, 0.f, 0.f, 0.f};

  // per-nt packed-B base (elements); advance by 512 elems per ks
  const __hip_bfloat16* bb[4];
#pragma unroll
  for (int nt = 0; nt < 4; ++nt)
    bb[nt] = wpk + ((size_t)(w * 4 + nt) * NKS * 64 + lane) * 8;

  auto loadA = [&](short8* a, int ks) {
    int k  = ks * 32 + q * 8;
    int kk = k >> 8;
    int lc = (k & 255) >> 3;
#pragma unroll
    for (int mt = 0; mt < 4; ++mt) {
      int rl = mt * 32 + row16 * 2 + kk;
      int pc = lc ^ ((rl >> 1) & 15);
      a[mt] = *(const short8*)(A_lds + rl * 512 + pc * 16);
    }
  };
  auto loadB = [&](short8* bf, int ks) {
#pragma unroll
    for (int nt = 0; nt < 4; ++nt)
      bf[nt] = *(const short8*)(bb[nt] + (size_t)ks * 512);
  };

  __syncthreads();   // staging landed (one-time vmcnt drain)

  short8 Af[3][4], Bf[3][4];
  loadA(Af[0], 0); loadB(Bf[0], 0);
  loadA(Af[1], 1); loadB(Bf[1], 1);

#pragma unroll
  for (int ks = 0; ks < NKS; ++ks) {
    const int cur = ks % 3;
    const int nxt = (ks + 2) % 3;
    if (ks < NKS - 2) { loadB(Bf[nxt], ks + 2); loadA(Af[nxt], ks + 2); }
#pragma unroll
    for (int mt = 0; mt < 4; ++mt)
#pragma unroll
      for (int nt = 0; nt < 4; ++nt)
        acc[mt][nt] = __builtin_amdgcn_mfma_f32_16x16x32_bf16(
            Af[cur][mt], Bf[cur][nt], acc[mt][nt], 0, 0, 0);
  }

  // ---- epilogue: rank-1 time term + bias, renorm over 256 ch, store
  __syncthreads();
  if (tid < 64) {
    const float* rs = rowsq + (size_t)b * LPAD + 2 * (Mblk + tid);
    float s5 = rs[0] + rs[1] + rs[2] + rs[3] + rs[4];
    time0_s[tid] = sqrtf(1.0f + s5);
    normsq_s[tid] = 0.0f;
  }
  __syncthreads();

  float w0v[4], bv[4];
#pragma unroll
  for (int nt = 0; nt < 4; ++nt) {
    int n = w * 64 + nt * 16 + row16;
    w0v[nt] = w0[n];
    bv[nt]  = bvec[1 + n];
  }

#pragma unroll
  for (int mt = 0; mt < 4; ++mt) {
    f32x4 t4 = *(const f32x4*)&time0_s[mt * 16 + q * 4];
#pragma unroll
    for (int nt = 0; nt < 4; ++nt)
#pragma unroll
      for (int r = 0; r < 4; ++r)
        acc[mt][nt][r] = acc[mt][nt][r] + t4[r] * w0v[nt] + bv[nt];
#pragma unroll
    for (int r = 0; r < 4; ++r) {
      float ps = 0.f;
#pragma unroll
      for (int nt = 0; nt < 4; ++nt) ps += acc[mt][nt][r] * acc[mt][nt][r];
      ps += __shfl_xor(ps, 1);
      ps += __shfl_xor(ps, 2);
      ps += __shfl_xor(ps, 4);
      ps += __shfl_xor(ps, 8);
      if (row16 == 0) atomicAdd(&normsq_s[mt * 16 + q * 4 + r], ps);
    }
  }
  __syncthreads();

#pragma unroll
  for (int mt = 0; mt < 4; ++mt) {
#pragma unroll
    for (int r = 0; r < 4; ++r) {
      int m = mt * 16 + q * 4 + r;
      float nsq  = normsq_s[m];
      float norm = sqrtf(nsq);
      float scale = fminf(1.0f, 1000.0f / fmaxf(norm, 1e-8f));
      size_t ob = ((size_t)b * NF + Mblk + m) * 257;
#pragma unroll
      for (int nt = 0; nt < 4; ++nt) {
        int n = w * 64 + nt * 16 + row16;
        out[ob + 1 + n] = acc[mt][nt][r] * scale;
      }
    }
  }
  if (tid < 64) {
    float nsq  = normsq_s[tid];
    float norm = sqrtf(nsq);
    float scale = fminf(1.0f, 1000.0f / fmaxf(norm, 1e-8f));
    size_t ob = ((size_t)b * NF + Mblk + tid) * 257;
    out[ob] = sqrtf(1.0f + scale * scale * nsq);
  }
}

// ---------------- safety fallback (only if ws too small): naive fp32
__global__ void fallback_kernel(const float* __restrict__ x,
                                const float* __restrict__ W,
                                const float* __restrict__ bvec,
                                float* __restrict__ out) {
  int fid = blockIdx.x;
  int b = fid >> 12;
  int g = fid & (NF - 1);
  __shared__ float patch[1280];
  __shared__ float red[256];
  int tid = threadIdx.x;
  float ss = 0.f;
  for (int k = tid; k < 1280; k += 256) {
    int kk = k >> 8, c = k & 255;
    int t = 2 * g + kk - 2;
    float v = (t >= 0 && t < LEN) ? x[((size_t)b * LEN + t) * CIN + 1 + c] : 0.f;
    patch[k] = v;
    ss += v * v;
  }
  red[tid] = ss;
  __syncthreads();
  for (int off = 128; off > 0; off >>= 1) {
    if (tid < off) red[tid] += red[tid + off];
    __syncthreads();
  }
  float time0 = sqrtf(1.f + red[0]);
  __syncthreads();
  const float* wrow = W + (size_t)(tid + 1) * 1281;
  float acc = time0 * wrow[0] + bvec[tid + 1];
  for (int k = 0; k < 1280; ++k) acc += wrow[1 + k] * patch[k];
  red[tid] = acc * acc;
  __syncthreads();
  for (int off = 128; off > 0; off >>= 1) {
    if (tid < off) red[tid] += red[tid + off];
    __syncthreads();
  }
  float nsq = red[0];
  float norm = sqrtf(nsq);
  float scale = fminf(1.f, 1000.f / fmaxf(norm, 1e-8f));
  size_t ob = ((size_t)b * NF + g) * 257;
  out[ob + 1 + tid] = acc * scale;
  if (tid == 0) out[ob] = sqrtf(1.f + scale * scale * nsq);
}

extern "C" void kernel_launch(void* const* d_in, const int* in_sizes, int n_in,
                              void* d_out, int out_size, void* d_ws, size_t ws_size,
                              hipStream_t stream) {
  const float* x  = (const float*)d_in[0];
  const float* W  = (const float*)d_in[1];
  const float* bv = (const float*)d_in[2];
  float* out = (float*)d_out;

  if (ws_size >= WS_NEED) {
    char* ws = (char*)d_ws;
    __hip_bfloat16* xs  = (__hip_bfloat16*)ws;
    float* rowsq        = (float*)(ws + RSQ_OFF);
    __hip_bfloat16* wpk = (__hip_bfloat16*)(ws + WPK_OFF);
    float* w0           = (float*)(ws + W0_OFF);
    prep_w_kernel<<<160, 256, 0, stream>>>(W, wpk, w0);
    prep_x_kernel<<<8193, 256, 0, stream>>>(x, xs, rowsq);
    lorentz_gemm_kernel<<<BATCH * (NF / MT), 256, 0, stream>>>(xs, wpk, rowsq, w0, bv, out);
  } else {
    fallback_kernel<<<BATCH * NF, 256, 0, stream>>>(x, W, bv, out);
  }
}